// Round 2
// baseline (2709.866 us; speedup 1.0000x reference)
//
#include <hip/hip_runtime.h>
#include <cstdint>

#define NN 100000
#define CH 128

// -------- degree: deg[i] = #edges with dst==i --------
__global__ void k_deg(const int* __restrict__ dst, float* __restrict__ deg, int E) {
    int e = blockIdx.x * blockDim.x + threadIdx.x;
    if (e < E) atomicAdd(&deg[dst[e]], 1.0f);
}

// -------- scatter-add: msg[dst] += feat[src], 32 threads per edge (4 ch each) --------
__global__ void k_scatter(const float* __restrict__ feat, const int* __restrict__ src,
                          const int* __restrict__ dst, float* msg, int E) {
    int t = blockIdx.x * blockDim.x + threadIdx.x;
    int e = t >> 5;
    if (e >= E) return;
    int q = (t & 31) << 2;
    int s = src[e], d = dst[e];
    const float4 v = *reinterpret_cast<const float4*>(feat + (size_t)s * CH + q);
    float* m = msg + (size_t)d * CH + q;
    atomicAdd(m + 0, v.x);
    atomicAdd(m + 1, v.y);
    atomicAdd(m + 2, v.z);
    atomicAdd(m + 3, v.w);
}

// -------- fused SAGE layer: out = relu( (msg/max(deg,1)) @ Wl + skip @ Wr + b ) --------
// Block = 128 threads (one output channel each), MT nodes per block.
// Activation addresses are blockIdx-derived (wave-uniform) -> scalar loads (SMEM pipe);
// only W row loads hit the vector memory pipe (L2-hot, coalesced).
// NOTE: `out` may alias `msg` (layer 2). Each block touches only its own MT rows,
// and the __syncthreads() below guarantees all reads of those rows complete
// (both waves of the block) before any thread overwrites them.
template<int MT>
__global__ __launch_bounds__(128) void k_layer(
    const float* msg, const float* __restrict__ deg,
    const float* __restrict__ skip,
    const float* __restrict__ Wl, const float* __restrict__ Wr,
    const float* __restrict__ bias, float* out)
{
    const int c = threadIdx.x;            // output channel, 0..127
    const int node0 = blockIdx.x * MT;    // uniform across block

    float accA[MT], accX[MT];
#pragma unroll
    for (int m = 0; m < MT; ++m) { accA[m] = 0.0f; accX[m] = 0.0f; }

#pragma unroll 4
    for (int k = 0; k < CH; ++k) {
        float wl = Wl[k * CH + c];
        float wr = Wr[k * CH + c];
#pragma unroll
        for (int m = 0; m < MT; ++m) {
            accA[m] = fmaf(msg[(size_t)(node0 + m) * CH + k], wl, accA[m]);
            accX[m] = fmaf(skip[(size_t)(node0 + m) * CH + k], wr, accX[m]);
        }
    }

    __syncthreads();   // out may alias msg: all reads must complete before writes

    float bv = bias[c];
#pragma unroll
    for (int m = 0; m < MT; ++m) {
        float dv = deg[node0 + m];
        float inv = 1.0f / fmaxf(dv, 1.0f);
        float v = fmaf(accA[m], inv, accX[m] + bv);
        v = fmaxf(v, 0.0f);               // both layers end in ReLU
        out[(size_t)(node0 + m) * CH + c] = v;
    }
}

// -------- FC head: out[i] = sigmoid(dot(h[i], Wfc) + bfc), one wave per node --------
__global__ __launch_bounds__(256) void k_fc(const float* __restrict__ h, const float* __restrict__ w,
                                            const float* __restrict__ b, float* __restrict__ out, int n) {
    int node = blockIdx.x * 4 + (threadIdx.x >> 6);
    if (node >= n) return;
    int lane = threadIdx.x & 63;
    const float2 a  = *reinterpret_cast<const float2*>(h + (size_t)node * CH + lane * 2);
    const float2 ww = *reinterpret_cast<const float2*>(w + lane * 2);
    float v = a.x * ww.x + a.y * ww.y;
#pragma unroll
    for (int off = 32; off > 0; off >>= 1) v += __shfl_down(v, off);
    if (lane == 0) {
        float z = v + b[0];
        out[node] = 1.0f / (1.0f + expf(-z));
    }
}

extern "C" void kernel_launch(void* const* d_in, const int* in_sizes, int n_in,
                              void* d_out, int out_size, void* d_ws, size_t ws_size,
                              hipStream_t stream) {
    const float* x   = (const float*)d_in[0];
    const int*   ei  = (const int*)d_in[1];
    const float* W1l = (const float*)d_in[2];
    const float* W1r = (const float*)d_in[3];
    const float* b1  = (const float*)d_in[4];
    const float* W2l = (const float*)d_in[5];
    const float* W2r = (const float*)d_in[6];
    const float* b2  = (const float*)d_in[7];
    const float* Wfc = (const float*)d_in[8];
    const float* bfc = (const float*)d_in[9];

    const int E = in_sizes[1] / 2;
    const int* src = ei;
    const int* dst = ei + E;

    // workspace: msg [NN*CH] f32 | h1 [NN*CH] f32 | deg [NN] f32   (~103 MB)
    float* msg = (float*)d_ws;
    float* h1  = msg + (size_t)NN * CH;
    float* deg = h1 + (size_t)NN * CH;

    hipMemsetAsync(msg, 0, (size_t)NN * CH * sizeof(float), stream);
    hipMemsetAsync(deg, 0, (size_t)NN * sizeof(float), stream);

    k_deg<<<(E + 255) / 256, 256, 0, stream>>>(dst, deg, E);

    long long st = (long long)E * 32;
    int sblocks = (int)((st + 255) / 256);

    // layer 1
    k_scatter<<<sblocks, 256, 0, stream>>>(x, src, dst, msg, E);
    k_layer<8><<<NN / 8, 128, 0, stream>>>(msg, deg, x, W1l, W1r, b1, h1);

    // layer 2 (h2 written back into msg buffer — safe: per-block read-then-barrier-then-write)
    hipMemsetAsync(msg, 0, (size_t)NN * CH * sizeof(float), stream);
    k_scatter<<<sblocks, 256, 0, stream>>>(h1, src, dst, msg, E);
    k_layer<8><<<NN / 8, 128, 0, stream>>>(msg, deg, h1, W2l, W2r, b2, msg);

    // FC head
    k_fc<<<(NN + 3) / 4, 256, 0, stream>>>(msg, Wfc, bfc, (float*)d_out, NN);
}

// Round 3
// 589.765 us; speedup vs baseline: 4.5948x; 4.5948x over previous
//
#include <hip/hip_runtime.h>
#include <cstdint>

#define NN 100000
#define CH 128
#define MT 8
#define SCAN_B 256

// ================= CSR build =================

__global__ void k_count(const int* __restrict__ dst, int* __restrict__ cnt, int E) {
    int e = blockIdx.x * blockDim.x + threadIdx.x;
    if (e < E) atomicAdd(&cnt[dst[e]], 1);
}

// per-block exclusive scan (Hillis-Steele), emits block totals
__global__ void k_scan_block(const int* __restrict__ cnt, int* __restrict__ rowptr,
                             int* __restrict__ bsum, int n) {
    __shared__ int tmp[SCAN_B];
    int i = blockIdx.x * SCAN_B + threadIdx.x;
    int v = (i < n) ? cnt[i] : 0;
    tmp[threadIdx.x] = v;
    __syncthreads();
    for (int off = 1; off < SCAN_B; off <<= 1) {
        int t = (threadIdx.x >= off) ? tmp[threadIdx.x - off] : 0;
        __syncthreads();
        tmp[threadIdx.x] += t;
        __syncthreads();
    }
    if (i < n) rowptr[i] = tmp[threadIdx.x] - v;      // exclusive within block
    if (threadIdx.x == SCAN_B - 1) bsum[blockIdx.x] = tmp[SCAN_B - 1];
}

// single-block exclusive scan of block totals (nb <= 512)
__global__ void k_scan_tops(int* __restrict__ bsum, int nb) {
    __shared__ int tmp[512];
    int v = (threadIdx.x < nb) ? bsum[threadIdx.x] : 0;
    tmp[threadIdx.x] = v;
    __syncthreads();
    for (int off = 1; off < 512; off <<= 1) {
        int t = (threadIdx.x >= off) ? tmp[threadIdx.x - off] : 0;
        __syncthreads();
        tmp[threadIdx.x] += t;
        __syncthreads();
    }
    if (threadIdx.x < nb) bsum[threadIdx.x] = tmp[threadIdx.x] - v;
}

__global__ void k_scan_add(int* __restrict__ rowptr, const int* __restrict__ bsum, int n, int E) {
    int i = blockIdx.x * SCAN_B + threadIdx.x;
    if (i < n) rowptr[i] += bsum[blockIdx.x];
    if (i == 0) rowptr[n] = E;
}

__global__ void k_fill(const int* __restrict__ src, const int* __restrict__ dst,
                       const int* __restrict__ rowptr, int* __restrict__ cursor,
                       int* __restrict__ csr, int E) {
    int e = blockIdx.x * blockDim.x + threadIdx.x;
    if (e >= E) return;
    int d = dst[e];
    int slot = rowptr[d] + atomicAdd(&cursor[d], 1);
    csr[slot] = src[e];
}

// ================= fused SAGE layer =================
// Block = 128 threads (one output channel each), MT=8 nodes per block.
// Phase 1: CSR gather-mean -> LDS agg[8][128]; stage skip rows -> LDS sk[8][128].
// Phase 2: dual GEMM (agg@Wl + skip@Wr) with float4 LDS broadcasts + coalesced W loads.
// FC=true (layer 2): fuse the [128->1] head + sigmoid, write 1 float per node.
template<bool FC>
__global__ __launch_bounds__(128) void k_layer(
    const float* __restrict__ feat,
    const int* __restrict__ rowptr, const int* __restrict__ csr,
    const float* __restrict__ Wl, const float* __restrict__ Wr,
    const float* __restrict__ bias,
    const float* __restrict__ Wfc, const float* __restrict__ bfc,
    float* __restrict__ out)
{
    __shared__ __align__(16) float agg[MT][CH];
    __shared__ __align__(16) float sk[MT][CH];
    __shared__ float red[2];

    const int c = threadIdx.x;              // output channel 0..127
    const int node0 = blockIdx.x * MT;      // uniform across block

    // ---- Phase 1: gather-mean (batch-4 for ILP) ----
    for (int m = 0; m < MT; ++m) {
        const int node = node0 + m;
        const int r0 = rowptr[node], r1 = rowptr[node + 1];
        float s = 0.0f;
        int r = r0;
        for (; r + 4 <= r1; r += 4) {
            int i0 = csr[r], i1 = csr[r + 1], i2 = csr[r + 2], i3 = csr[r + 3];
            float v0 = feat[(size_t)i0 * CH + c];
            float v1 = feat[(size_t)i1 * CH + c];
            float v2 = feat[(size_t)i2 * CH + c];
            float v3 = feat[(size_t)i3 * CH + c];
            s += (v0 + v1) + (v2 + v3);
        }
        for (; r < r1; ++r) s += feat[(size_t)csr[r] * CH + c];
        const float invd = 1.0f / fmaxf((float)(r1 - r0), 1.0f);
        agg[m][c] = s * invd;
        sk[m][c]  = feat[(size_t)node * CH + c];
    }
    __syncthreads();

    // ---- Phase 2: dual GEMM ----
    float accA[MT], accX[MT];
#pragma unroll
    for (int m = 0; m < MT; ++m) { accA[m] = 0.0f; accX[m] = 0.0f; }

#pragma unroll 2
    for (int k = 0; k < CH; k += 4) {
        const float wl0 = Wl[(k + 0) * CH + c];
        const float wl1 = Wl[(k + 1) * CH + c];
        const float wl2 = Wl[(k + 2) * CH + c];
        const float wl3 = Wl[(k + 3) * CH + c];
        const float wr0 = Wr[(k + 0) * CH + c];
        const float wr1 = Wr[(k + 1) * CH + c];
        const float wr2 = Wr[(k + 2) * CH + c];
        const float wr3 = Wr[(k + 3) * CH + c];
#pragma unroll
        for (int m = 0; m < MT; ++m) {
            const float4 a  = *reinterpret_cast<const float4*>(&agg[m][k]);
            const float4 sx = *reinterpret_cast<const float4*>(&sk[m][k]);
            accA[m] = fmaf(a.w, wl3, fmaf(a.z, wl2, fmaf(a.y, wl1, fmaf(a.x, wl0, accA[m]))));
            accX[m] = fmaf(sx.w, wr3, fmaf(sx.z, wr2, fmaf(sx.y, wr1, fmaf(sx.x, wr0, accX[m]))));
        }
    }

    // ---- Epilogue ----
    const float bv = bias[c];
    const float wfc = FC ? Wfc[c] : 0.0f;
    for (int m = 0; m < MT; ++m) {
        float v = fmaxf(accA[m] + accX[m] + bv, 0.0f);   // both layers end in ReLU
        if (!FC) {
            out[(size_t)(node0 + m) * CH + c] = v;
        } else {
            float p = v * wfc;
#pragma unroll
            for (int off = 32; off; off >>= 1) p += __shfl_down(p, off);
            if ((c & 63) == 0) red[c >> 6] = p;
            __syncthreads();
            if (c == 0) {
                float z = red[0] + red[1] + bfc[0];
                out[node0 + m] = 1.0f / (1.0f + expf(-z));
            }
            __syncthreads();
        }
    }
}

// ================= launch =================

extern "C" void kernel_launch(void* const* d_in, const int* in_sizes, int n_in,
                              void* d_out, int out_size, void* d_ws, size_t ws_size,
                              hipStream_t stream) {
    const float* x   = (const float*)d_in[0];
    const int*   ei  = (const int*)d_in[1];
    const float* W1l = (const float*)d_in[2];
    const float* W1r = (const float*)d_in[3];
    const float* b1  = (const float*)d_in[4];
    const float* W2l = (const float*)d_in[5];
    const float* W2r = (const float*)d_in[6];
    const float* b2  = (const float*)d_in[7];
    const float* Wfc = (const float*)d_in[8];
    const float* bfc = (const float*)d_in[9];

    const int E = in_sizes[1] / 2;
    const int* src = ei;
    const int* dst = ei + E;

    // workspace layout (h1 first -> 16B-aligned rows for float4 gathers): ~55 MB
    float* h1   = (float*)d_ws;                 // NN*CH f32
    int* cnt    = (int*)(h1 + (size_t)NN * CH); // NN        (degree counts, reused as fill cursor)
    int* rowptr = cnt + NN;                     // NN+1
    int* bsum   = rowptr + NN + 1;              // 512
    int* csr    = bsum + 512;                   // E

    const int nb = (NN + SCAN_B - 1) / SCAN_B;  // 391

    // CSR build
    hipMemsetAsync(cnt, 0, (size_t)NN * sizeof(int), stream);
    k_count<<<(E + 255) / 256, 256, 0, stream>>>(dst, cnt, E);
    k_scan_block<<<nb, SCAN_B, 0, stream>>>(cnt, rowptr, bsum, NN);
    k_scan_tops<<<1, 512, 0, stream>>>(bsum, nb);
    k_scan_add<<<nb, SCAN_B, 0, stream>>>(rowptr, bsum, NN, E);
    hipMemsetAsync(cnt, 0, (size_t)NN * sizeof(int), stream);  // -> cursor
    k_fill<<<(E + 255) / 256, 256, 0, stream>>>(src, dst, rowptr, cnt, csr, E);

    // layer 1: x -> h1
    k_layer<false><<<NN / MT, 128, 0, stream>>>(x, rowptr, csr, W1l, W1r, b1, Wfc, bfc, h1);
    // layer 2 + FC head: h1 -> sigmoid logits
    k_layer<true><<<NN / MT, 128, 0, stream>>>(h1, rowptr, csr, W2l, W2r, b2, Wfc, bfc, (float*)d_out);
}

// Round 4
// 340.509 us; speedup vs baseline: 7.9583x; 1.7320x over previous
//
#include <hip/hip_runtime.h>
#include <cstdint>

#define NN 100000
#define CH 128
#define NT_BLK 64
#define SCAN_B 256

typedef __bf16 bf16x8 __attribute__((ext_vector_type(8)));
typedef __bf16 bf16x4 __attribute__((ext_vector_type(4)));
typedef float  f32x4  __attribute__((ext_vector_type(4)));

// ================= CSR build =================

__global__ void k_count(const int* __restrict__ dst, int* __restrict__ cnt, int E) {
    int e = blockIdx.x * blockDim.x + threadIdx.x;
    if (e < E) atomicAdd(&cnt[dst[e]], 1);
}

__global__ void k_scan_block(const int* __restrict__ cnt, int* __restrict__ rowptr,
                             int* __restrict__ bsum, int n) {
    __shared__ int tmp[SCAN_B];
    int i = blockIdx.x * SCAN_B + threadIdx.x;
    int v = (i < n) ? cnt[i] : 0;
    tmp[threadIdx.x] = v;
    __syncthreads();
    for (int off = 1; off < SCAN_B; off <<= 1) {
        int t = (threadIdx.x >= off) ? tmp[threadIdx.x - off] : 0;
        __syncthreads();
        tmp[threadIdx.x] += t;
        __syncthreads();
    }
    if (i < n) rowptr[i] = tmp[threadIdx.x] - v;
    if (threadIdx.x == SCAN_B - 1) bsum[blockIdx.x] = tmp[SCAN_B - 1];
}

__global__ void k_scan_tops(int* __restrict__ bsum, int nb) {
    __shared__ int tmp[512];
    int v = (threadIdx.x < nb) ? bsum[threadIdx.x] : 0;
    tmp[threadIdx.x] = v;
    __syncthreads();
    for (int off = 1; off < 512; off <<= 1) {
        int t = (threadIdx.x >= off) ? tmp[threadIdx.x - off] : 0;
        __syncthreads();
        tmp[threadIdx.x] += t;
        __syncthreads();
    }
    if (threadIdx.x < nb) bsum[threadIdx.x] = tmp[threadIdx.x] - v;
}

__global__ void k_scan_add(int* __restrict__ rowptr, const int* __restrict__ bsum, int n, int E) {
    int i = blockIdx.x * SCAN_B + threadIdx.x;
    if (i < n) rowptr[i] += bsum[blockIdx.x];
    if (i == 0) rowptr[n] = E;
}

__global__ void k_fill(const int* __restrict__ src, const int* __restrict__ dst,
                       const int* __restrict__ rowptr, int* __restrict__ cursor,
                       int* __restrict__ csr, int E) {
    int e = blockIdx.x * blockDim.x + threadIdx.x;
    if (e >= E) return;
    int d = dst[e];
    int slot = rowptr[d] + atomicAdd(&cursor[d], 1);
    csr[slot] = src[e];
}

// ================= weight pre-convert to bf16 MFMA fragments =================
// B = [Wl;Wr] (256x128). Fragment layout [layer][kt:8][nt:8][lane:64][8 bf16]:
//   element i of (kt,nt,lane) = B[kt*32 + (lane>>4)*8 + i][nt*16 + (lane&15)]
__global__ void k_wconv(const float* __restrict__ W1l, const float* __restrict__ W1r,
                        const float* __restrict__ W2l, const float* __restrict__ W2r,
                        __bf16* __restrict__ wB) {
    int tid = blockIdx.x * blockDim.x + threadIdx.x;   // 8192 total
    int l    = tid >> 12;
    int rem  = tid & 4095;
    int kt   = rem >> 9;
    int nt   = (rem >> 6) & 7;
    int lane = rem & 63;
    const float* Wl = l ? W2l : W1l;
    const float* Wr = l ? W2r : W1r;
    int n  = nt * 16 + (lane & 15);
    int k0 = kt * 32 + (lane >> 4) * 8;
    bf16x8 v;
#pragma unroll
    for (int i = 0; i < 8; ++i) {
        int k = k0 + i;
        float f = (k < CH) ? Wl[k * CH + n] : Wr[(k - CH) * CH + n];
        v[i] = (__bf16)f;
    }
    *reinterpret_cast<bf16x8*>(wB + (size_t)tid * 8) = v;
}

// ================= fused SAGE layer (MFMA) =================
// Block: 256 thr / 4 waves, 64 nodes. Phase 1: CSR gather-mean (f32) -> bf16 LDS
// A-tile [64][256] (agg k=0..127, skip k=128..255), XOR-swizzled (G4: row stride
// 512B would be 16-way conflict on ds_read_b128). Phase 2: wave w computes nodes
// w*16..+15 x 128 ch as 8 column-tiles, K=256 via 8 MFMA k-steps. B-frags are
// single 16B coalesced loads from the pre-swizzled wB (L2-hot).
// FC=true: fused [128->1] head + sigmoid (16-lane shfl_xor reduce).
template<bool FC>
__global__ __launch_bounds__(256) void k_layer(
    const float* __restrict__ feat,
    const int* __restrict__ rowptr, const int* __restrict__ csr,
    const bf16x8* __restrict__ wfrag,
    const float* __restrict__ bias,
    const float* __restrict__ Wfc, const float* __restrict__ bfc,
    float* __restrict__ out)
{
    __shared__ unsigned short a_lds[NT_BLK * 256];   // 32 KB
    char* lb = (char*)a_lds;
    const int tid = threadIdx.x;
    const int node0 = blockIdx.x * NT_BLK;

    // ---- Phase 1: gather-mean ----
    const int g = tid >> 5;      // 8 groups of 32 lanes; group handles one node/iter
    const int q = tid & 31;      // q*4 = f32 channel
    for (int it = 0; it < 8; ++it) {
        const int r = it * 8 + g;            // local row 0..63
        const int node = node0 + r;
        const int swz = (r & 7) << 4;
        float4 s  = make_float4(0.f, 0.f, 0.f, 0.f);
        float4 sv = make_float4(0.f, 0.f, 0.f, 0.f);
        if (node < NN) {
            const int r0 = rowptr[node], r1 = rowptr[node + 1];
            int rr = r0;
            for (; rr + 2 <= r1; rr += 2) {
                int i0 = csr[rr], i1 = csr[rr + 1];
                const float4 v0 = *reinterpret_cast<const float4*>(feat + (size_t)i0 * CH + q * 4);
                const float4 v1 = *reinterpret_cast<const float4*>(feat + (size_t)i1 * CH + q * 4);
                s.x += v0.x + v1.x; s.y += v0.y + v1.y;
                s.z += v0.z + v1.z; s.w += v0.w + v1.w;
            }
            if (rr < r1) {
                int i0 = csr[rr];
                const float4 v0 = *reinterpret_cast<const float4*>(feat + (size_t)i0 * CH + q * 4);
                s.x += v0.x; s.y += v0.y; s.z += v0.z; s.w += v0.w;
            }
            const float invd = 1.0f / fmaxf((float)(r1 - r0), 1.0f);
            s.x *= invd; s.y *= invd; s.z *= invd; s.w *= invd;
            sv = *reinterpret_cast<const float4*>(feat + (size_t)node * CH + q * 4);
        }
        bf16x4 a, k2;
        a[0] = (__bf16)s.x;  a[1] = (__bf16)s.y;  a[2] = (__bf16)s.z;  a[3] = (__bf16)s.w;
        k2[0] = (__bf16)sv.x; k2[1] = (__bf16)sv.y; k2[2] = (__bf16)sv.z; k2[3] = (__bf16)sv.w;
        *reinterpret_cast<bf16x4*>(lb + r * 512 + ((q * 8) ^ swz)) = a;
        *reinterpret_cast<bf16x4*>(lb + r * 512 + ((256 + q * 8) ^ swz)) = k2;
    }
    __syncthreads();

    // ---- Phase 2: MFMA dual-GEMM (K=256 folded) ----
    const int lane = tid & 63;
    const int w = tid >> 6;
    const int row = w * 16 + (lane & 15);
    const int rswz = (row & 7) << 4;
    const int abase = row * 512;
    const int asub = (lane >> 4) * 16;

    f32x4 acc[8];
#pragma unroll
    for (int nt = 0; nt < 8; ++nt) { acc[nt][0] = 0.f; acc[nt][1] = 0.f; acc[nt][2] = 0.f; acc[nt][3] = 0.f; }

#pragma unroll
    for (int kt = 0; kt < 8; ++kt) {
        bf16x8 a = *reinterpret_cast<const bf16x8*>(lb + abase + ((kt * 64 + asub) ^ rswz));
        const bf16x8* bp = wfrag + kt * 512 + lane;
#pragma unroll
        for (int nt = 0; nt < 8; ++nt) {
            bf16x8 b = bp[nt * 64];
            acc[nt] = __builtin_amdgcn_mfma_f32_16x16x32_bf16(a, b, acc[nt], 0, 0, 0);
        }
    }

    // ---- Epilogue ----
    const int nbase = lane & 15;
    if (!FC) {
#pragma unroll
        for (int nt = 0; nt < 8; ++nt) {
            const float bv = bias[nt * 16 + nbase];
#pragma unroll
            for (int rr = 0; rr < 4; ++rr) {
                const int node = node0 + w * 16 + (lane >> 4) * 4 + rr;
                if (node < NN)
                    out[(size_t)node * CH + nt * 16 + nbase] = fmaxf(acc[nt][rr] + bv, 0.0f);
            }
        }
    } else {
        float p0 = 0.f, p1 = 0.f, p2 = 0.f, p3 = 0.f;
#pragma unroll
        for (int nt = 0; nt < 8; ++nt) {
            const float bv = bias[nt * 16 + nbase];
            const float wf = Wfc[nt * 16 + nbase];
            p0 += fmaxf(acc[nt][0] + bv, 0.0f) * wf;
            p1 += fmaxf(acc[nt][1] + bv, 0.0f) * wf;
            p2 += fmaxf(acc[nt][2] + bv, 0.0f) * wf;
            p3 += fmaxf(acc[nt][3] + bv, 0.0f) * wf;
        }
#pragma unroll
        for (int m = 1; m < 16; m <<= 1) {
            p0 += __shfl_xor(p0, m); p1 += __shfl_xor(p1, m);
            p2 += __shfl_xor(p2, m); p3 += __shfl_xor(p3, m);
        }
        if (nbase == 0) {
            const float bf = bfc[0];
            const int nb0 = node0 + w * 16 + (lane >> 4) * 4;
            float zz[4] = {p0, p1, p2, p3};
#pragma unroll
            for (int rr = 0; rr < 4; ++rr) {
                const int node = nb0 + rr;
                if (node < NN) out[node] = 1.0f / (1.0f + expf(-(zz[rr] + bf)));
            }
        }
    }
}

// ================= launch =================

extern "C" void kernel_launch(void* const* d_in, const int* in_sizes, int n_in,
                              void* d_out, int out_size, void* d_ws, size_t ws_size,
                              hipStream_t stream) {
    const float* x   = (const float*)d_in[0];
    const int*   ei  = (const int*)d_in[1];
    const float* W1l = (const float*)d_in[2];
    const float* W1r = (const float*)d_in[3];
    const float* b1  = (const float*)d_in[4];
    const float* W2l = (const float*)d_in[5];
    const float* W2r = (const float*)d_in[6];
    const float* b2  = (const float*)d_in[7];
    const float* Wfc = (const float*)d_in[8];
    const float* bfc = (const float*)d_in[9];

    const int E = in_sizes[1] / 2;
    const int* src = ei;
    const int* dst = ei + E;

    // ws: h1 [NN*CH f32] | wB [2*32768 bf16] | cnt [NN] | rowptr [NN+1] | bsum [512] | csr [E]
    float*  h1     = (float*)d_ws;
    __bf16* wB     = (__bf16*)(h1 + (size_t)NN * CH);
    int*    cnt    = (int*)(wB + 65536);
    int*    rowptr = cnt + NN;
    int*    bsum   = rowptr + NN + 1;
    int*    csr    = bsum + 512;

    const int nb = (NN + SCAN_B - 1) / SCAN_B;

    // CSR build
    hipMemsetAsync(cnt, 0, (size_t)NN * sizeof(int), stream);
    k_count<<<(E + 255) / 256, 256, 0, stream>>>(dst, cnt, E);
    k_scan_block<<<nb, SCAN_B, 0, stream>>>(cnt, rowptr, bsum, NN);
    k_scan_tops<<<1, 512, 0, stream>>>(bsum, nb);
    k_scan_add<<<nb, SCAN_B, 0, stream>>>(rowptr, bsum, NN, E);
    hipMemsetAsync(cnt, 0, (size_t)NN * sizeof(int), stream);
    k_fill<<<(E + 255) / 256, 256, 0, stream>>>(src, dst, rowptr, cnt, csr, E);

    // weights -> bf16 fragments
    k_wconv<<<32, 256, 0, stream>>>(W1l, W1r, W2l, W2r, wB);

    const int blocks = (NN + NT_BLK - 1) / NT_BLK;   // 1563
    // layer 1: x -> h1
    k_layer<false><<<blocks, 256, 0, stream>>>(x, rowptr, csr, (const bf16x8*)wB,
                                               b1, Wfc, bfc, h1);
    // layer 2 + FC head -> d_out
    k_layer<true><<<blocks, 256, 0, stream>>>(h1, rowptr, csr, (const bf16x8*)(wB + 32768),
                                              b2, Wfc, bfc, (float*)d_out);
}

// Round 5
// 294.469 us; speedup vs baseline: 9.2025x; 1.1563x over previous
//
#include <hip/hip_runtime.h>
#include <cstdint>

#define NN 100000
#define CH 128
#define NT_BLK 32
#define SCAN_B 256

typedef __bf16 bf16x8 __attribute__((ext_vector_type(8)));
typedef __bf16 bf16x4 __attribute__((ext_vector_type(4)));
typedef float  f32x4  __attribute__((ext_vector_type(4)));

__device__ __forceinline__ float b2f(unsigned short u) {
    union { unsigned int i; float f; } v; v.i = ((unsigned int)u) << 16; return v.f;
}

// ================= CSR build =================

__global__ void k_count(const int* __restrict__ dst, int* __restrict__ cnt, int E) {
    int e = blockIdx.x * blockDim.x + threadIdx.x;
    if (e < E) atomicAdd(&cnt[dst[e]], 1);
}

// per-block exclusive scan, emits block totals
__global__ void k_scan_block(const int* __restrict__ cnt, int* __restrict__ rowptr,
                             int* __restrict__ bsum, int n) {
    __shared__ int tmp[SCAN_B];
    int i = blockIdx.x * SCAN_B + threadIdx.x;
    int v = (i < n) ? cnt[i] : 0;
    tmp[threadIdx.x] = v;
    __syncthreads();
    for (int off = 1; off < SCAN_B; off <<= 1) {
        int t = (threadIdx.x >= off) ? tmp[threadIdx.x - off] : 0;
        __syncthreads();
        tmp[threadIdx.x] += t;
        __syncthreads();
    }
    if (i < n) rowptr[i] = tmp[threadIdx.x] - v;
    if (threadIdx.x == SCAN_B - 1) bsum[blockIdx.x] = tmp[SCAN_B - 1];
}

// fused: add prefix of block totals (each block sums bsum[0..bid-1] itself),
// and initialize the fill cursor to the row start (kills k_scan_tops + a memset).
__global__ void k_scan_add(int* __restrict__ rowptr, const int* __restrict__ bsum,
                           int* __restrict__ cursor, int n, int E) {
    __shared__ int sd[SCAN_B];
    const int t = threadIdx.x;
    int s = 0;
    for (int j = t; j < (int)blockIdx.x; j += SCAN_B) s += bsum[j];
    sd[t] = s;
    __syncthreads();
    for (int off = SCAN_B / 2; off > 0; off >>= 1) {
        if (t < off) sd[t] += sd[t + off];
        __syncthreads();
    }
    const int base = sd[0];
    int i = blockIdx.x * SCAN_B + t;
    if (i < n) {
        int v = rowptr[i] + base;
        rowptr[i] = v;
        cursor[i] = v;
    }
    if (i == 0) rowptr[n] = E;
}

__global__ void k_fill(const int* __restrict__ src, const int* __restrict__ dst,
                       int* __restrict__ cursor, int* __restrict__ csr, int E) {
    int e = blockIdx.x * blockDim.x + threadIdx.x;
    if (e >= E) return;
    int slot = atomicAdd(&cursor[dst[e]], 1);
    csr[slot] = src[e];
}

// ================= weight pre-convert to bf16 MFMA fragments =================
// B = [Wl;Wr] (256x128). Fragment layout [layer][kt:8][nt:8][lane:64][8 bf16]:
//   element i of (kt,nt,lane) = B[kt*32 + (lane>>4)*8 + i][nt*16 + (lane&15)]
__global__ void k_wconv(const float* __restrict__ W1l, const float* __restrict__ W1r,
                        const float* __restrict__ W2l, const float* __restrict__ W2r,
                        __bf16* __restrict__ wB) {
    int tid = blockIdx.x * blockDim.x + threadIdx.x;   // 8192 total
    int l    = tid >> 12;
    int rem  = tid & 4095;
    int kt   = rem >> 9;
    int nt   = (rem >> 6) & 7;
    int lane = rem & 63;
    const float* Wl = l ? W2l : W1l;
    const float* Wr = l ? W2r : W1r;
    int n  = nt * 16 + (lane & 15);
    int k0 = kt * 32 + (lane >> 4) * 8;
    bf16x8 v;
#pragma unroll
    for (int i = 0; i < 8; ++i) {
        int k = k0 + i;
        float f = (k < CH) ? Wl[k * CH + n] : Wr[(k - CH) * CH + n];
        v[i] = (__bf16)f;
    }
    *reinterpret_cast<bf16x8*>(wB + (size_t)tid * 8) = v;
}

// ================= fused SAGE layer (MFMA) =================
// Block: 256 thr / 4 waves, NT_BLK=32 nodes (16 KB LDS -> 8 blocks/CU, 32 waves).
// Phase 1: CSR gather-mean (f32 accum), unroll-4 independent row loads/lane;
//          bf16 A-tile [32][256] (agg k<128 | skip k>=128), XOR-swizzled (G4).
// Phase 2: wave w -> rows (w>>1)*16..+15, col-half (w&1): 4 nt-tiles, K=256.
// FT=float (layer1 reads f32 x) or ushort (layer2 reads bf16 h1).
// FC=true: fused [128->1] head + sigmoid; channel halves live in wave pairs,
// combined via small LDS buffer.
template<bool FC, typename FT>
__global__ __launch_bounds__(256) void k_layer(
    const FT* __restrict__ feat,
    const int* __restrict__ rowptr, const int* __restrict__ csr,
    const bf16x8* __restrict__ wfrag,
    const float* __restrict__ bias,
    const float* __restrict__ Wfc, const float* __restrict__ bfc,
    void* __restrict__ outv)
{
    __shared__ unsigned short a_lds[NT_BLK * 256];   // 16 KB
    __shared__ float red[4][16];
    char* lb = (char*)a_lds;
    const int tid = threadIdx.x;
    const int node0 = blockIdx.x * NT_BLK;

    // ---- Phase 1: gather-mean ----
    const int g = tid >> 5;      // 8 groups of 32 lanes
    const int q = tid & 31;      // q*4 = channel base (4 ch per lane)

    auto loadrow = [&](int idx) -> float4 {
        if constexpr (sizeof(FT) == 2) {
            const ushort4 u = *reinterpret_cast<const ushort4*>(
                (const unsigned short*)feat + (size_t)idx * CH + q * 4);
            return make_float4(b2f(u.x), b2f(u.y), b2f(u.z), b2f(u.w));
        } else {
            return *reinterpret_cast<const float4*>((const float*)feat + (size_t)idx * CH + q * 4);
        }
    };

#pragma unroll
    for (int it = 0; it < NT_BLK / 8; ++it) {
        const int r = it * 8 + g;            // local row 0..31
        const int node = node0 + r;
        const int swz = (r & 7) << 4;
        float4 s = make_float4(0.f, 0.f, 0.f, 0.f);
        bf16x4 k2 = {(__bf16)0.f, (__bf16)0.f, (__bf16)0.f, (__bf16)0.f};
        if (node < NN) {
            const int r0 = rowptr[node], r1 = rowptr[node + 1];
            int rr = r0;
            for (; rr + 4 <= r1; rr += 4) {
                const int i0 = csr[rr], i1 = csr[rr + 1], i2 = csr[rr + 2], i3 = csr[rr + 3];
                const float4 v0 = loadrow(i0), v1 = loadrow(i1), v2 = loadrow(i2), v3 = loadrow(i3);
                s.x += (v0.x + v1.x) + (v2.x + v3.x);
                s.y += (v0.y + v1.y) + (v2.y + v3.y);
                s.z += (v0.z + v1.z) + (v2.z + v3.z);
                s.w += (v0.w + v1.w) + (v2.w + v3.w);
            }
            for (; rr < r1; ++rr) {
                const float4 v = loadrow(csr[rr]);
                s.x += v.x; s.y += v.y; s.z += v.z; s.w += v.w;
            }
            const float invd = 1.0f / fmaxf((float)(r1 - r0), 1.0f);
            s.x *= invd; s.y *= invd; s.z *= invd; s.w *= invd;
            if constexpr (sizeof(FT) == 2) {
                const ushort4 u = *reinterpret_cast<const ushort4*>(
                    (const unsigned short*)feat + (size_t)node * CH + q * 4);
                k2 = *reinterpret_cast<const bf16x4*>(&u);   // exact bit copy
            } else {
                const float4 sv = *reinterpret_cast<const float4*>((const float*)feat + (size_t)node * CH + q * 4);
                k2[0] = (__bf16)sv.x; k2[1] = (__bf16)sv.y; k2[2] = (__bf16)sv.z; k2[3] = (__bf16)sv.w;
            }
        }
        bf16x4 a;
        a[0] = (__bf16)s.x; a[1] = (__bf16)s.y; a[2] = (__bf16)s.z; a[3] = (__bf16)s.w;
        *reinterpret_cast<bf16x4*>(lb + r * 512 + ((q * 8) ^ swz)) = a;
        *reinterpret_cast<bf16x4*>(lb + r * 512 + ((256 + q * 8) ^ swz)) = k2;
    }
    __syncthreads();

    // ---- Phase 2: MFMA dual-GEMM (K=256 folded) ----
    const int lane = tid & 63;
    const int w = tid >> 6;
    const int rows16 = (w >> 1) * 16;        // row half
    const int ntbase = (w & 1) * 4;          // col half (4 nt-tiles of 16)
    const int row = rows16 + (lane & 15);
    const int rswz = (row & 7) << 4;
    const int abase = row * 512;
    const int asub = (lane >> 4) * 16;

    f32x4 acc[4];
#pragma unroll
    for (int nt = 0; nt < 4; ++nt) { acc[nt][0] = 0.f; acc[nt][1] = 0.f; acc[nt][2] = 0.f; acc[nt][3] = 0.f; }

#pragma unroll
    for (int kt = 0; kt < 8; ++kt) {
        const bf16x8 a = *reinterpret_cast<const bf16x8*>(lb + abase + ((kt * 64 + asub) ^ rswz));
        const bf16x8* bp = wfrag + kt * 512 + ntbase * 64 + lane;
#pragma unroll
        for (int nt = 0; nt < 4; ++nt) {
            const bf16x8 b = bp[nt * 64];
            acc[nt] = __builtin_amdgcn_mfma_f32_16x16x32_bf16(a, b, acc[nt], 0, 0, 0);
        }
    }

    // ---- Epilogue ----
    const int nbase = lane & 15;
    if (!FC) {
        __bf16* out = (__bf16*)outv;
#pragma unroll
        for (int nt = 0; nt < 4; ++nt) {
            const int ch = (ntbase + nt) * 16 + nbase;
            const float bv = bias[ch];
#pragma unroll
            for (int rr = 0; rr < 4; ++rr) {
                const int node = node0 + rows16 + (lane >> 4) * 4 + rr;
                if (node < NN)
                    out[(size_t)node * CH + ch] = (__bf16)fmaxf(acc[nt][rr] + bv, 0.0f);
            }
        }
    } else {
        float* out = (float*)outv;
        float p[4] = {0.f, 0.f, 0.f, 0.f};
#pragma unroll
        for (int nt = 0; nt < 4; ++nt) {
            const int ch = (ntbase + nt) * 16 + nbase;
            const float bv = bias[ch];
            const float wf = Wfc[ch];
#pragma unroll
            for (int rr = 0; rr < 4; ++rr)
                p[rr] += fmaxf(acc[nt][rr] + bv, 0.0f) * wf;
        }
#pragma unroll
        for (int m = 1; m < 16; m <<= 1) {
#pragma unroll
            for (int rr = 0; rr < 4; ++rr) p[rr] += __shfl_xor(p[rr], m);
        }
        if (nbase == 0) {
#pragma unroll
            for (int rr = 0; rr < 4; ++rr)
                red[w][(lane >> 4) * 4 + rr] = p[rr];
        }
        __syncthreads();
        if (tid < NT_BLK) {
            const int rloc = tid;
            const float z = (rloc < 16 ? red[0][rloc] + red[1][rloc]
                                       : red[2][rloc - 16] + red[3][rloc - 16]) + bfc[0];
            const int node = node0 + rloc;
            if (node < NN) out[node] = 1.0f / (1.0f + expf(-z));
        }
    }
}

// ================= launch =================

extern "C" void kernel_launch(void* const* d_in, const int* in_sizes, int n_in,
                              void* d_out, int out_size, void* d_ws, size_t ws_size,
                              hipStream_t stream) {
    const float* x   = (const float*)d_in[0];
    const int*   ei  = (const int*)d_in[1];
    const float* W1l = (const float*)d_in[2];
    const float* W1r = (const float*)d_in[3];
    const float* b1  = (const float*)d_in[4];
    const float* W2l = (const float*)d_in[5];
    const float* W2r = (const float*)d_in[6];
    const float* b2  = (const float*)d_in[7];
    const float* Wfc = (const float*)d_in[8];
    const float* bfc = (const float*)d_in[9];

    const int E = in_sizes[1] / 2;
    const int* src = ei;
    const int* dst = ei + E;

    // ws: h1 [NN*CH bf16] | wB [2*32768 bf16] | cnt/cursor [NN] | rowptr [NN+1] | bsum [512] | csr [E]
    unsigned short* h1 = (unsigned short*)d_ws;
    __bf16* wB     = (__bf16*)(h1 + (size_t)NN * CH);
    int*    cnt    = (int*)(wB + 65536);
    int*    rowptr = cnt + NN;
    int*    bsum   = rowptr + NN + 1;
    int*    csr    = bsum + 512;

    const int nb = (NN + SCAN_B - 1) / SCAN_B;   // 391

    // CSR build (cnt -> rowptr; cursor = cnt reused, initialized by k_scan_add)
    hipMemsetAsync(cnt, 0, (size_t)NN * sizeof(int), stream);
    k_count<<<(E + 255) / 256, 256, 0, stream>>>(dst, cnt, E);
    k_scan_block<<<nb, SCAN_B, 0, stream>>>(cnt, rowptr, bsum, NN);
    k_scan_add<<<nb, SCAN_B, 0, stream>>>(rowptr, bsum, cnt, NN, E);
    k_fill<<<(E + 255) / 256, 256, 0, stream>>>(src, dst, cnt, csr, E);

    // weights -> bf16 fragments
    k_wconv<<<32, 256, 0, stream>>>(W1l, W1r, W2l, W2r, wB);

    const int blocks = (NN + NT_BLK - 1) / NT_BLK;   // 3125
    // layer 1: x (f32) -> h1 (bf16)
    k_layer<false, float><<<blocks, 256, 0, stream>>>(
        x, rowptr, csr, (const bf16x8*)wB, b1, Wfc, bfc, h1);
    // layer 2 + FC head: h1 (bf16) -> sigmoid probs (f32)
    k_layer<true, unsigned short><<<blocks, 256, 0, stream>>>(
        h1, rowptr, csr, (const bf16x8*)(wB + 32768), b2, Wfc, bfc, d_out);
}